// Round 5
// baseline (360.664 us; speedup 1.0000x reference)
//
#include <hip/hip_runtime.h>

typedef _Float16 f16;
typedef _Float16 f16x4 __attribute__((ext_vector_type(4)));
typedef _Float16 f16x8 __attribute__((ext_vector_type(8)));
typedef float f32x4 __attribute__((ext_vector_type(4)));
typedef unsigned int u32;

// Problem dims (fixed by setup_inputs)
#define NB   8
#define SEQ  2048
#define DQ_  512
#define DKV_ 768
#define HD_  512

__device__ __forceinline__ void gll16(const void* g, void* l) {
  __builtin_amdgcn_global_load_lds(
      (const __attribute__((address_space(1))) u32*)g,
      (__attribute__((address_space(3))) u32*)l, 16, 0, 0);
}

// ---------------- K0b: transposing f32 -> f16 cast for weights ----------------
// in: [K][N] f32, out: [N][K] f16
__global__ __launch_bounds__(256) void cast_transpose(const float* __restrict__ in,
                                                      f16* __restrict__ out,
                                                      int K, int N) {
  int i = blockIdx.x * 256 + threadIdx.x;
  if (i >= K * N) return;
  int n = i / K, k = i % K;
  out[i] = (f16)in[k * N + n];
}

// ---------------- K1: fused GEMM + LayerNorm ----------------
// Block: 512 thr (8 waves). Tile: 64 rows x 512 cols (full row -> in-block LN).
// Register-limited to 1 block/CU (acc 64 AGPR + ~80 VGPR), so latency must be
// hidden IN-block: T14 async-split X prefetch (regs double-buffer, issue next
// strip's loads before compute). W fragments direct from global (L2-resident).
// Xs stride 148 halves (296B = 40 mod 128) -> <=2-way conflicts (free).
// proj 2 (v) writes output TRANSPOSED per batch: vt[b][c][l].
__global__ __launch_bounds__(512) void proj_ln(
    const float* __restrict__ xq, const float* __restrict__ xkv,
    const f16* __restrict__ wqt, const f16* __restrict__ wkt, const f16* __restrict__ wvt,
    const float* __restrict__ bq, const float* __restrict__ gq, const float* __restrict__ beq,
    const float* __restrict__ bk, const float* __restrict__ gk, const float* __restrict__ bek,
    const float* __restrict__ bv, const float* __restrict__ gv, const float* __restrict__ bev,
    f16* __restrict__ outq, f16* __restrict__ outk, f16* __restrict__ outvt)
{
  // LDS: Xs [64][148] f16 = 18944 B; epilogue reuses [0,36864) as trans
  // [256][72]. red/mus/rss after 36864.
  __shared__ char smem[36864 + 4096 + 512];
  f16* Xs    = (f16*)smem;                    // [64][148]
  f16* trans = (f16*)smem;                    // [256][72]  (epilogue reuse)
  float* red = (float*)(smem + 36864);        // [64][8][2]
  float* mus = (float*)(smem + 36864 + 4096); // [64]
  float* rss = mus + 64;                      // [64]

  const int proj = blockIdx.x >> 8;
  const int tile = blockIdx.x & 255;
  const float* X; const f16* Wt; const float *bias, *gam, *bet; f16* out; int KD;
  if (proj == 0)      { X = xq;  Wt = wqt; bias = bq; gam = gq; bet = beq; out = outq;  KD = 512; }
  else if (proj == 1) { X = xkv; Wt = wkt; bias = bk; gam = gk; bet = bek; out = outk;  KD = 768; }
  else                { X = xkv; Wt = wvt; bias = bv; gam = gv; bet = bev; out = outvt; KD = 768; }

  const int row0 = tile * 64;
  const int tid = threadIdx.x;
  const int w = tid >> 6;
  const int lane = tid & 63;
  const int g = lane >> 4, tt = lane & 15;

  // Hoisted per-thread pointers
  const int rX = tid >> 3, cX = (tid & 7) * 16;
  const float* xrow = X + (size_t)(row0 + rX) * KD + cX;
  const f16* wrow[4];
  #pragma unroll
  for (int n = 0; n < 4; ++n)
    wrow[n] = Wt + (size_t)(w * 64 + n * 16 + tt) * KD + g * 8;

  f32x4 acc[4][4] = {};

  const int nstrip = KD >> 7;                 // 4 (q) or 6 (kv)
  // prologue: load strip 0 into regs
  float4 xa = *(const float4*)(xrow);
  float4 xb = *(const float4*)(xrow + 4);
  float4 xc = *(const float4*)(xrow + 8);
  float4 xd = *(const float4*)(xrow + 12);
  const float* xp = xrow + 128;

  for (int st = 0; st < nstrip; ++st) {
    {  // convert current regs -> LDS
      f16x8 h0, h1;
      h0[0] = (f16)xa.x; h0[1] = (f16)xa.y; h0[2] = (f16)xa.z; h0[3] = (f16)xa.w;
      h0[4] = (f16)xb.x; h0[5] = (f16)xb.y; h0[6] = (f16)xb.z; h0[7] = (f16)xb.w;
      h1[0] = (f16)xc.x; h1[1] = (f16)xc.y; h1[2] = (f16)xc.z; h1[3] = (f16)xc.w;
      h1[4] = (f16)xd.x; h1[5] = (f16)xd.y; h1[6] = (f16)xd.z; h1[7] = (f16)xd.w;
      *(f16x8*)&Xs[rX * 148 + cX]     = h0;
      *(f16x8*)&Xs[rX * 148 + cX + 8] = h1;
    }
    __syncthreads();
    if (st + 1 < nstrip) {   // T14: issue next strip's loads before compute
      xa = *(const float4*)(xp);
      xb = *(const float4*)(xp + 4);
      xc = *(const float4*)(xp + 8);
      xd = *(const float4*)(xp + 12);
      xp += 128;
    }
    #pragma unroll
    for (int s = 0; s < 4; ++s) {
      f16x8 af[4], bf[4];
      #pragma unroll
      for (int n = 0; n < 4; ++n)
        bf[n] = *(const f16x8*)(wrow[n] + s * 32);
      #pragma unroll
      for (int m = 0; m < 4; ++m)
        af[m] = *(const f16x8*)&Xs[(m * 16 + tt) * 148 + s * 32 + g * 8];
      #pragma unroll
      for (int n = 0; n < 4; ++n)
        #pragma unroll
        for (int m = 0; m < 4; ++m)
          acc[m][n] = __builtin_amdgcn_mfma_f32_16x16x32_f16(af[m], bf[n], acc[m][n], 0, 0, 0);
    }
    #pragma unroll
    for (int n = 0; n < 4; ++n) wrow[n] += 128;
    __syncthreads();
  }

  // ---- epilogue: bias add + LayerNorm stats (f32) ----
  float bias4[4], gam4[4], bet4[4];
  #pragma unroll
  for (int n = 0; n < 4; ++n) {
    int c = w * 64 + n * 16 + tt;
    bias4[n] = bias[c]; gam4[n] = gam[c]; bet4[n] = bet[c];
  }
  float rsum[4][4], rsq[4][4];
  #pragma unroll
  for (int m = 0; m < 4; ++m)
    #pragma unroll
    for (int j = 0; j < 4; ++j) { rsum[m][j] = 0.f; rsq[m][j] = 0.f; }
  #pragma unroll
  for (int m = 0; m < 4; ++m)
    #pragma unroll
    for (int n = 0; n < 4; ++n)
      #pragma unroll
      for (int j = 0; j < 4; ++j) {
        float h = acc[m][n][j] + bias4[n];
        acc[m][n][j] = h;
        rsum[m][j] += h; rsq[m][j] += h * h;
      }
  // reduce across the 16 lanes sharing each row (lane bits 0..3)
  #pragma unroll
  for (int mk = 1; mk < 16; mk <<= 1)
    #pragma unroll
    for (int m = 0; m < 4; ++m)
      #pragma unroll
      for (int j = 0; j < 4; ++j) {
        rsum[m][j] += __shfl_xor(rsum[m][j], mk);
        rsq[m][j]  += __shfl_xor(rsq[m][j], mk);
      }
  if (tt == 0) {
    #pragma unroll
    for (int m = 0; m < 4; ++m)
      #pragma unroll
      for (int j = 0; j < 4; ++j) {
        int r = m * 16 + g * 4 + j;
        red[(r * 8 + w) * 2 + 0] = rsum[m][j];
        red[(r * 8 + w) * 2 + 1] = rsq[m][j];
      }
  }
  __syncthreads();
  if (tid < 64) {   // cross-wave combine: one thread per row
    float s = 0.f, sq = 0.f;
    #pragma unroll
    for (int w2 = 0; w2 < 8; ++w2) {
      s  += red[(tid * 8 + w2) * 2 + 0];
      sq += red[(tid * 8 + w2) * 2 + 1];
    }
    float mu = s * (1.f / 512.f);
    float var = sq * (1.f / 512.f) - mu * mu;
    mus[tid] = mu;
    rss[tid] = rsqrtf(var + 1e-5f);
  }
  __syncthreads();
  #pragma unroll
  for (int m = 0; m < 4; ++m)
    #pragma unroll
    for (int j = 0; j < 4; ++j) {
      int r = m * 16 + g * 4 + j;
      float mu = mus[r], rs = rss[r];
      #pragma unroll
      for (int n = 0; n < 4; ++n)
        acc[m][n][j] = (acc[m][n][j] - mu) * rs * gam4[n] + bet4[n];
    }

  if (proj != 2) {
    // straight f16 store: out[row][col]
    #pragma unroll
    for (int m = 0; m < 4; ++m)
      #pragma unroll
      for (int j = 0; j < 4; ++j) {
        int r = row0 + m * 16 + g * 4 + j;
        #pragma unroll
        for (int n = 0; n < 4; ++n)
          out[(size_t)r * 512 + w * 64 + n * 16 + tt] = (f16)acc[m][n][j];
      }
  } else {
    // transposed store via LDS: vt[b][c][l], two 256-col chunks
    const int bch = row0 >> 11, l0 = row0 & 2047;
    __syncthreads();
    for (int half = 0; half < 2; ++half) {
      if ((w >> 2) == half) {
        #pragma unroll
        for (int m = 0; m < 4; ++m)
          #pragma unroll
          for (int n = 0; n < 4; ++n)
            #pragma unroll
            for (int j = 0; j < 4; ++j)
              trans[((w & 3) * 64 + n * 16 + tt) * 72 + (m * 16 + g * 4 + j)] =
                  (f16)acc[m][n][j];
      }
      __syncthreads();
      {
        int c = tid >> 1, ii = tid & 1;
        size_t gb = (size_t)bch * (512 * 2048) + (size_t)(half * 256 + c) * 2048
                    + l0 + ii * 32;
        #pragma unroll
        for (int q2 = 0; q2 < 4; ++q2)
          *(f16x8*)&out[gb + q2 * 8] = *(const f16x8*)&trans[c * 72 + ii * 32 + q2 * 8];
      }
      __syncthreads();
    }
  }
}

// ---------------- K2/K4: batched NT GEMM, compile-time dims ----------------
// C[b][m][n] = sum_k A[b][m][k] * Bt[b][n][k]  (+ resid), lda = ldb = K.
// 128x128 tile, BK=64, 4 waves in 2x2, mfma 16x16x32 f16. Full K-unroll:
// staging addresses hoisted, kt folds into gll16's 13-bit imm (max 3968B<4096).
template <bool RESID, typename CT, int K, int tilesM, int tilesN, int N>
__global__ __launch_bounds__(256) void gemm_nt(
    const f16* __restrict__ A, const f16* __restrict__ Bt,
    CT* __restrict__ C, const float* __restrict__ resid)
{
  constexpr size_t sA = (size_t)SEQ * K;
  constexpr size_t sB = (size_t)tilesN * 128 * K;
  constexpr size_t sC = (size_t)SEQ * N;
  constexpr int bpb = tilesM * tilesN;
  constexpr int nwg = bpb * NB;
  __shared__ f16 As[128 * 64];
  __shared__ f16 Bs[128 * 64];
  // T1 XCD swizzle (nwg % 8 == 0 at both call sites)
  const int orig = blockIdx.x;
  const int bid = (orig & 7) * (nwg / 8) + (orig >> 3);
  const int b = bid / bpb;
  const int t = bid - b * bpb;
  const int tm = t % tilesM, tn = t / tilesM;
  const int tid = threadIdx.x, w = tid >> 6, lane = tid & 63;
  const int wr = w >> 1, wc = w & 1;
  const int g = lane >> 4, tt = lane & 15;

  const f16* Ab  = A  + (size_t)b * sA + (size_t)tm * 128 * K;
  const f16* Btb = Bt + (size_t)b * sB + (size_t)tn * 128 * K;
  // Hoisted staging addresses (chunk-swizzle on SOURCE, linear LDS dest)
  const f16* aS[4]; const f16* bS[4]; int ld[4];
  #pragma unroll
  for (int i = 0; i < 4; ++i) {
    int oi = i * 4096 + tid * 16;
    int r = oi >> 7, c = (oi >> 4) & 7, cs = c ^ (r & 7);
    ld[i] = oi;
    aS[i] = Ab  + (size_t)r * K + cs * 8;
    bS[i] = Btb + (size_t)r * K + cs * 8;
  }
  // Hoisted fragment LDS offsets (halves)
  int aOff[4][2], bOff[4][2];
  #pragma unroll
  for (int m = 0; m < 4; ++m) {
    int R = wr * 64 + m * 16 + tt;
    #pragma unroll
    for (int kk = 0; kk < 2; ++kk)
      aOff[m][kk] = R * 64 + (((kk * 4 + g) ^ (R & 7)) * 8);
  }
  #pragma unroll
  for (int n = 0; n < 4; ++n) {
    int R = wc * 64 + n * 16 + tt;
    #pragma unroll
    for (int kk = 0; kk < 2; ++kk)
      bOff[n][kk] = R * 64 + (((kk * 4 + g) ^ (R & 7)) * 8);
  }

  f32x4 acc[4][4] = {};
  #pragma unroll
  for (int kt = 0; kt < K; kt += 64) {
    #pragma unroll
    for (int i = 0; i < 4; ++i) {
      gll16(aS[i] + kt, (char*)As + ld[i]);
      gll16(bS[i] + kt, (char*)Bs + ld[i]);
    }
    __syncthreads();
    #pragma unroll
    for (int kk = 0; kk < 2; ++kk) {
      f16x8 af[4], bf[4];
      #pragma unroll
      for (int m = 0; m < 4; ++m) af[m] = *(const f16x8*)&As[aOff[m][kk]];
      #pragma unroll
      for (int n = 0; n < 4; ++n) bf[n] = *(const f16x8*)&Bs[bOff[n][kk]];
      #pragma unroll
      for (int n = 0; n < 4; ++n)
        #pragma unroll
        for (int m = 0; m < 4; ++m)
          acc[m][n] = __builtin_amdgcn_mfma_f32_16x16x32_f16(af[m], bf[n], acc[m][n], 0, 0, 0);
    }
    __syncthreads();
  }
  const size_t Cb = (size_t)b * sC;
  #pragma unroll
  for (int m = 0; m < 4; ++m)
    #pragma unroll
    for (int j = 0; j < 4; ++j) {
      int r = tm * 128 + wr * 64 + m * 16 + g * 4 + j;
      #pragma unroll
      for (int n = 0; n < 4; ++n) {
        int c = tn * 128 + wc * 64 + n * 16 + tt;
        size_t idx = Cb + (size_t)r * N + c;
        float v = acc[m][n][j];
        if (RESID) v += resid[idx];
        C[idx] = (CT)v;
      }
    }
}

// ---------------- K3: row softmax, IN-PLACE on f16 S ----------------
__global__ __launch_bounds__(256) void softmax_rows(f16* __restrict__ SP)
{
  __shared__ float sred[4];
  const size_t row = blockIdx.x;
  f16x8* Pr = (f16x8*)(SP + row * 2048);
  const int tid = threadIdx.x, w = tid >> 6, lane = tid & 63;
  f16x8 v = Pr[tid];
  float f[8];
  #pragma unroll
  for (int j = 0; j < 8; ++j) f[j] = (float)v[j];
  float mx = f[0];
  #pragma unroll
  for (int j = 1; j < 8; ++j) mx = fmaxf(mx, f[j]);
  #pragma unroll
  for (int mk = 1; mk < 64; mk <<= 1) mx = fmaxf(mx, __shfl_xor(mx, mk));
  if (lane == 0) sred[w] = mx;
  __syncthreads();
  mx = fmaxf(fmaxf(sred[0], sred[1]), fmaxf(sred[2], sred[3]));
  __syncthreads();
  float e[8], s = 0.f;
  #pragma unroll
  for (int j = 0; j < 8; ++j) { e[j] = __expf(f[j] - mx); s += e[j]; }
  #pragma unroll
  for (int mk = 1; mk < 64; mk <<= 1) s += __shfl_xor(s, mk);
  if (lane == 0) sred[w] = s;
  __syncthreads();
  s = sred[0] + sred[1] + sred[2] + sred[3];
  float inv = 1.f / s;
  f16x8 p;
  #pragma unroll
  for (int j = 0; j < 8; ++j) p[j] = (f16)(e[j] * inv);
  Pr[tid] = p;
}

// ---------------- host launcher ----------------
extern "C" void kernel_launch(void* const* d_in, const int* in_sizes, int n_in,
                              void* d_out, int out_size, void* d_ws, size_t ws_size,
                              hipStream_t stream) {
  const float* qs   = (const float*)d_in[0];   // [8,2048,512]
  const float* kv   = (const float*)d_in[1];   // [8,2048,768]
  const float* Wq   = (const float*)d_in[2];
  const float* bq   = (const float*)d_in[3];
  const float* gq   = (const float*)d_in[4];
  const float* beq  = (const float*)d_in[5];
  const float* Wk   = (const float*)d_in[6];
  const float* bk   = (const float*)d_in[7];
  const float* gk   = (const float*)d_in[8];
  const float* bek  = (const float*)d_in[9];
  const float* Wv   = (const float*)d_in[10];
  const float* bv   = (const float*)d_in[11];
  const float* gv   = (const float*)d_in[12];
  const float* bev  = (const float*)d_in[13];
  float* out = (float*)d_out;

  // ---- workspace layout (peak 119,537,664 B ~= 114 MB) ----
  char* ws = (char*)d_ws;
  f16* q16  = (f16*)(ws + 0);            // 16,777,216 B  [8,2048,512]
  f16* k16  = (f16*)(ws + 16777216);     // 16,777,216 B  [8,2048,512]
  f16* vt   = (f16*)(ws + 33554432);     // 16,777,216 B  [8,512,2048]
  f16* Wqt  = (f16*)(ws + 50331648);     //    524,288 B  [512][512]
  f16* Wkt  = (f16*)(ws + 50855936);     //    786,432 B  [512][768]
  f16* Wvt  = (f16*)(ws + 51642368);     //    786,432 B  [512][768]
  f16* S    = (f16*)(ws + 52428800);     // 67,108,864 B  [8,2048,2048] f16
                                         // ends 119,537,664 B

  // K0: weight transpose+cast (small)
  cast_transpose<<<1024, 256, 0, stream>>>(Wq, Wqt, 512, 512);
  cast_transpose<<<1536, 256, 0, stream>>>(Wk, Wkt, 768, 512);
  cast_transpose<<<1536, 256, 0, stream>>>(Wv, Wvt, 768, 512);

  // K1: fused projections + LN (768 blocks = 3 projections x 256 tiles)
  proj_ln<<<768, 512, 0, stream>>>(qs, kv, Wqt, Wkt, Wvt,
                                   bq, gq, beq, bk, gk, bek, bv, gv, bev,
                                   q16, k16, vt);

  // K2: S[b,l,L] = sum_c k[b,l,c] * q[b,L,c]   (NT, f16 out)
  gemm_nt<false, f16, 512, 16, 16, 2048><<<2048, 256, 0, stream>>>(
      k16, q16, S, nullptr);

  // K3: row softmax over L, in-place f16
  softmax_rows<<<16384, 256, 0, stream>>>(S);

  // K4: out[b,l,c] = sum_L P[b,l,L] * vt[b,c,L] + qs[b,l,c]
  gemm_nt<true, float, 2048, 16, 4, 512><<<512, 256, 0, stream>>>(
      S, vt, out, qs);
}